// Round 10
// baseline (362.290 us; speedup 1.0000x reference)
//
#include <hip/hip_runtime.h>
#include <hip/hip_bf16.h>
#include <math.h>

#define N_NODES 50000
#define E_EDGES 400000
#define EN_TOT  (E_EDGES + N_NODES)
#define F_IN    128
#define HC      384
#define CLASSES 40
#define LOG2E   1.44269504088896f

typedef short short8 __attribute__((ext_vector_type(8)));
typedef float floatx4 __attribute__((ext_vector_type(4)));
typedef float floatx2 __attribute__((ext_vector_type(2)));
typedef unsigned int uint;

struct u3 { uint x, y, z; };   // 12B, align 4

__device__ __forceinline__ float bf2f(unsigned short u) {
  union { unsigned int i; float f; } x; x.i = ((unsigned int)u) << 16; return x.f;
}
__device__ __forceinline__ unsigned short f2bf(float f) {
  union { float f; unsigned int i; } x; x.f = f;
  unsigned int r = x.i + 0x7fffu + ((x.i >> 16) & 1u);
  return (unsigned short)(r >> 16);
}
__device__ __forceinline__ float fin(float v) {        // NaN/Inf -> 0 (no-op on healthy path)
  return (fabsf(v) < 1e30f) ? v : 0.f;
}
__device__ __forceinline__ float rdw(const void* p, int idx, int fp32) {
  return fp32 ? ((const float*)p)[idx] : bf2f(((const unsigned short*)p)[idx]);
}

#if __has_builtin(__builtin_amdgcn_exp2f)
#define EXP2F(x) __builtin_amdgcn_exp2f(x)
#else
#define EXP2F(x) exp2f(x)
#endif

// 16-lane reduce broadcast via v_add/max_f32_dpp butterfly (row=16 aligned groups).
#if __has_builtin(__builtin_amdgcn_update_dpp)
#define DPP_ADD(w, ctrl) \
  (w += __int_as_float(__builtin_amdgcn_update_dpp(0, __float_as_int(w), ctrl, 0xf, 0xf, true)))
#define REDUCE16(w) do { DPP_ADD(w, 0xB1); DPP_ADD(w, 0x4E); DPP_ADD(w, 0x141); DPP_ADD(w, 0x140); } while (0)
#define DPP_MAXF(w, ctrl) do { float _t = __int_as_float(__builtin_amdgcn_update_dpp(0, \
    __float_as_int(w), ctrl, 0xf, 0xf, true)); w = fmaxf(w, _t); } while (0)
#define RED16MAX(w) do { DPP_MAXF(w, 0xB1); DPP_MAXF(w, 0x4E); DPP_MAXF(w, 0x141); DPP_MAXF(w, 0x140); } while (0)
#else
#define REDUCE16(w) do { w += __shfl_xor(w, 1); w += __shfl_xor(w, 2); \
                         w += __shfl_xor(w, 4); w += __shfl_xor(w, 8); } while (0)
#define RED16MAX(w) do { w = fmaxf(w, __shfl_xor(w, 1)); w = fmaxf(w, __shfl_xor(w, 2)); \
                         w = fmaxf(w, __shfl_xor(w, 4)); w = fmaxf(w, __shfl_xor(w, 8)); } while (0)
#endif

// swizzled row layout for GEMM outputs feeding k_edge:
// channel c (0..383): k = c>>7, L = (c&127)>>1, b = c&1 -> byte off = L*12 + k*4 + b*2.
// Lane L of k_edge reads its 3 channel-pair dwords as ONE dwordx3 at row*768 + L*12.

__global__ void k_sentinel(float* out, int n) {
  int i = blockIdx.x * 256 + threadIdx.x;
  if (i < n) out[i] = 111.0f;
}

// ---------------- fused: zero counts/cursor + dtype detect (block 0, wave 0) ----
__global__ void k_detect_zero(const unsigned short* __restrict__ x, int* __restrict__ flag,
                              int* __restrict__ counts, int* __restrict__ cursor) {
  int i = blockIdx.x * 256 + threadIdx.x;
  if (i < N_NODES) { counts[i] = 0; cursor[i] = 0; }
  if (blockIdx.x == 0 && threadIdx.x < 64) {
    int L = threadIdx.x;
    int sane = 0;
#pragma unroll
    for (int t = 0; t < 4; ++t) {
      unsigned short u = x[(size_t)(L * 4 + t) * 2];
      unsigned int mag = u & 0x7FFFu;
      unsigned int e   = (u >> 7) & 0xFFu;
      if (mag == 0u || (e >= 96u && e <= 159u)) sane++;
    }
    sane += __shfl_xor(sane, 1);
    sane += __shfl_xor(sane, 2);
    sane += __shfl_xor(sane, 4);
    sane += __shfl_xor(sane, 8);
    sane += __shfl_xor(sane, 16);
    sane += __shfl_xor(sane, 32);
    if (L == 0) flag[0] = (sane < 179) ? 1 : 0;   // 1 => inputs are fp32
  }
}

__global__ void k_count(const int* __restrict__ ei, int* __restrict__ counts) {
  int e = blockIdx.x * 256 + threadIdx.x;
  if (e >= EN_TOT) return;
  int dst = (e < E_EDGES) ? ei[E_EDGES + e] : (e - E_EDGES);
  if ((unsigned)dst < N_NODES) atomicAdd(&counts[dst], 1);
}

__global__ void k_scan1(const int* __restrict__ counts, int* __restrict__ row_start,
                        int* __restrict__ bsum) {
  int b = blockIdx.x, tid = threadIdx.x;
  int i = b * 1024 + tid;
  int v = (i < N_NODES) ? counts[i] : 0;
  int lane = tid & 63, w = tid >> 6;
  int x = v;
#pragma unroll
  for (int d = 1; d < 64; d <<= 1) { int t = __shfl_up(x, d); if (lane >= d) x += t; }
  __shared__ int wsum[16];
  if (lane == 63) wsum[w] = x;
  __syncthreads();
  if (w == 0) {
    int y = (lane < 16) ? wsum[lane] : 0;
#pragma unroll
    for (int d = 1; d < 16; d <<= 1) { int t = __shfl_up(y, d); if (lane >= d) y += t; }
    if (lane < 16) wsum[lane] = y;
  }
  __syncthreads();
  if (w > 0) x += wsum[w - 1];
  if (i < N_NODES) row_start[i + 1] = x;
  if (tid == 1023) bsum[b] = x;
}

// fused scan2+scan3: every block redundantly scans the 49 block sums (cheap).
__global__ void k_scan23(int* __restrict__ row_start, const int* __restrict__ bsum, int nb) {
  int b = blockIdx.x, tid = threadIdx.x;
  __shared__ int sadd;
  if (tid < 64) {
    int lane = tid;
    int x = (lane < nb) ? bsum[lane] : 0;
#pragma unroll
    for (int d = 1; d < 64; d <<= 1) { int t = __shfl_up(x, d); if (lane >= d) x += t; }
    int pre = __shfl(x, (b > 0) ? (b - 1) : 0);
    if (tid == 0) sadd = (b > 0) ? pre : 0;
  }
  __syncthreads();
  int add = sadd;
  int i = b * 1024 + tid;
  if (i < N_NODES) row_start[i + 1] += add;
  if (i == 0) row_start[0] = 0;
}

// stores PRE-MULTIPLIED byte offsets (src*768).
__global__ void k_fill(const int* __restrict__ ei, const int* __restrict__ row_start,
                       int* __restrict__ cursor, int* __restrict__ csr_off) {
  int e = blockIdx.x * 256 + threadIdx.x;
  if (e >= EN_TOT) return;
  int src, dst;
  if (e < E_EDGES) { src = ei[e]; dst = ei[E_EDGES + e]; }
  else             { src = dst = e - E_EDGES; }
  if ((unsigned)dst >= N_NODES) return;
  int sv = ((unsigned)src < N_NODES) ? src : 0;
  int pos = atomicAdd(&cursor[dst], 1);
  int slot = row_start[dst] + pos;
  if ((unsigned)slot < EN_TOT) csr_off[slot] = sv * 768;
}

// ---------------- pack weights into MFMA frag order + att/bias f32 prepack ------
#define PK_J1 (F_IN * HC)          // 49152
#define PK_J2 (2 * PK_J1)          // 98304
#define PK_J3 (PK_J2 + HC * HC)    // 245760
#define PK_J4 (PK_J3 + HC * HC)    // 393216
#define PK_J5 (PK_J4 + HC * 32)    // 405504
#define PK_J6 (PK_J5 + 32 * 48)    // 407040 (W4 [32x40] zero-padded to 48 cols)
#define PK_EX 3144                 // att1,att2,bias1,bias2 (768 ea) + b3(32) + b4(40)
#define PK_TOT (PK_J6 + PK_EX)
// att/bias lane-major layout: idx i = L*6 + 2k + b  <->  channel c = 2L + 128k + b.
__global__ void k_pack_all(const void* __restrict__ Wl1, const void* __restrict__ Wr1,
                           const void* __restrict__ Wl2, const void* __restrict__ Wr2,
                           const void* __restrict__ W3, const void* __restrict__ W4,
                           const void* __restrict__ a1_, const void* __restrict__ a2_,
                           const void* __restrict__ b1_, const void* __restrict__ b2_,
                           const void* __restrict__ b3_, const void* __restrict__ b4_,
                           unsigned short* __restrict__ BpL1, unsigned short* __restrict__ BpR1,
                           unsigned short* __restrict__ BpL2, unsigned short* __restrict__ BpR2,
                           unsigned short* __restrict__ Bp3, unsigned short* __restrict__ Bp4,
                           float* __restrict__ attp1, float* __restrict__ attp2,
                           float* __restrict__ biasp1, float* __restrict__ biasp2,
                           float* __restrict__ b3p, float* __restrict__ b4p,
                           const int* __restrict__ flagp) {
  int gid = blockIdx.x * 256 + threadIdx.x;
  if (gid >= PK_TOT) return;
  int fp32 = flagp[0];
  if (gid >= PK_J6) {                       // f32 extras
    int i = gid - PK_J6;
    if (i < 3072) {
      int seg = i / 768, r = i % 768;
      int L = r / 6, q = r % 6, k = q >> 1, b = q & 1;
      int c = 2 * L + 128 * k + b;
      if (seg == 0)      attp1[r]  = fin(rdw(a1_, c, fp32)) * LOG2E;
      else if (seg == 1) attp2[r]  = fin(rdw(a2_, c, fp32)) * LOG2E;
      else if (seg == 2) biasp1[r] = fin(rdw(b1_, c, fp32));
      else               biasp2[r] = fin(rdw(b2_, c, fp32));
    } else if (i < 3104) b3p[i - 3072] = fin(rdw(b3_, i - 3072, fp32));
    else                 b4p[i - 3104] = fin(rdw(b4_, i - 3104, fp32));
    return;
  }
  const void* src; unsigned short* dst; int NT, NCOL, idx;
  if (gid < PK_J2)      { NT = 24; NCOL = 384; if (gid < PK_J1) { src = Wl1; dst = BpL1; idx = gid; }
                                               else             { src = Wr1; dst = BpR1; idx = gid - PK_J1; } }
  else if (gid < PK_J4) { NT = 24; NCOL = 384; if (gid < PK_J3) { src = Wl2; dst = BpL2; idx = gid - PK_J2; }
                                               else             { src = Wr2; dst = BpR2; idx = gid - PK_J3; } }
  else if (gid < PK_J5) { NT = 2;  NCOL = 32;  src = W3; dst = Bp3; idx = gid - PK_J4; }
  else                  { NT = 3;  NCOL = 40;  src = W4; dst = Bp4; idx = gid - PK_J5; }
  int j  = idx & 7;
  int L  = (idx >> 3) & 63;
  int t  = idx >> 9;       // kt*NT + nt
  int nt = t % NT;
  int kt = t / NT;
  int k  = kt * 32 + ((L >> 4) * 8) + j;
  int n  = nt * 16 + (L & 15);
  float v = (n < NCOL) ? rdw(src, k * NCOL + n, fp32) : 0.f;
  dst[idx] = f2bf(fin(v));
}

// ---------------- dual GEMM: 32-row tile, 2-buffer B prefetch -------------------
// Round-9 change: 3 B buffers -> 2. gfx950 has a UNIFIED VGPR/AGPR file, so the
// third buffer's 24 regs/wave directly cost resident waves; round-8's edge
// lesson (wave-level latency hiding beats register-level) applies here too.
// AF=1: A may be fp32 -> convert in the ONCE-PER-BLOCK staging loop.
#define LOADB(dst, kt) do { _Pragma("unroll") for (int n = 0; n < 6; ++n) \
    dst[n] = ((const short8*)Bp)[((size_t)((kt) * 24 + nt0 + n)) * 64 + lane]; } while (0)
#define DOMFMA(bf, kt) do { \
    short8 af[2]; \
    _Pragma("unroll") for (int mf = 0; mf < 2; ++mf) { \
      int row = mf * 16 + rsel; \
      int col = (kt) * 64 + kk16 * 16; \
      af[mf] = *(const short8*)(smem + row * RS + (col ^ ((row & 7) << 4))); } \
    _Pragma("unroll") for (int n = 0; n < 6; ++n) \
      _Pragma("unroll") for (int mf = 0; mf < 2; ++mf) \
        acc[mf][n] = __builtin_amdgcn_mfma_f32_16x16x32_bf16(af[mf], bf[n], acc[mf][n], 0, 0, 0); } while (0)

template<int NK, int AF>
__global__ __launch_bounds__(256, 4) void k_gemm2(const void* __restrict__ A_,
                       const unsigned short* __restrict__ BpL,
                       const unsigned short* __restrict__ BpR,
                       unsigned short* __restrict__ CL, unsigned short* __restrict__ CR,
                       const int* __restrict__ flagp) {
  constexpr int RS  = NK * 64;         // A row stride (bf16 bytes)
  constexpr int NST = NK / 2;          // staging iters (32 rows x RS / 4096B)
  __shared__ __align__(16) char smem[32 * 776];   // 24832B >= 32*RS (NK<=12)
  int which = blockIdx.x & 1;
  int bt    = blockIdx.x >> 1;
  const unsigned short* Bp = which ? BpR : BpL;
  unsigned short* C        = which ? CR  : CL;
  int fp32 = AF ? flagp[0] : 0;
  int tid  = threadIdx.x;
  int wave = tid >> 6, lane = tid & 63;
  int m0   = bt * 32;

  // ---- stage A tile (reg-staged, once; fp32 converted here; tail clamped) ----
  {
    uint4 v[NST];
#pragma unroll
    for (int i = 0; i < NST; ++i) {
      int o   = (i * 256 + tid) * 16;
      int row = o / RS;
      int rem = o - row * RS;
      int rg  = m0 + row; if (rg >= N_NODES) rg = N_NODES - 1;
      if (AF && fp32) {
        const float* p = (const float*)((const char*)A_ + ((size_t)rg * RS + rem) * 2);
        floatx4 f0 = *(const floatx4*)p;
        floatx4 f1 = *(const floatx4*)(p + 4);
        short8 o8;
#pragma unroll
        for (int j = 0; j < 4; ++j) { o8[j] = (short)f2bf(f0[j]); o8[4 + j] = (short)f2bf(f1[j]); }
        v[i] = *(uint4*)&o8;
      } else {
        v[i] = *(const uint4*)((const char*)A_ + (size_t)rg * RS + rem);
      }
    }
#pragma unroll
    for (int i = 0; i < NST; ++i) {
      int o   = (i * 256 + tid) * 16;
      int row = o / RS;
      int rem = o - row * RS;
      *(uint4*)(smem + row * RS + (rem ^ ((row & 7) << 4))) = v[i];
    }
  }

  int nt0  = wave * 6;
  int kk16 = (lane >> 4);
  int rsel = lane & 15;
  floatx4 acc[2][6];
#pragma unroll
  for (int mf = 0; mf < 2; ++mf)
#pragma unroll
    for (int n = 0; n < 6; ++n) acc[mf][n] = (floatx4){0.f, 0.f, 0.f, 0.f};

  short8 b0[6], b1[6];
  LOADB(b0, 0);                  // prefetch kt=0 before the A barrier
  __syncthreads();               // A tile ready

#pragma unroll
  for (int kt = 0; kt < NK; ++kt) {
    if ((kt & 1) == 0) {
      if (kt + 1 < NK) LOADB(b1, kt + 1);
      DOMFMA(b0, kt);
    } else {
      if (kt + 1 < NK) LOADB(b0, kt + 1);
      DOMFMA(b1, kt);
    }
  }

  // ---- epilogue: LDS re-staged wide stores (swizzled row layout) ----
  __syncthreads();
  int qr = lane >> 4, ccol = lane & 15;
#pragma unroll
  for (int n = 0; n < 6; ++n) {
    int c    = (nt0 + n) * 16 + ccol;
    int soff = ((c & 127) >> 1) * 12 + (c >> 7) * 4 + (c & 1) * 2;
#pragma unroll
    for (int mf = 0; mf < 2; ++mf)
#pragma unroll
      for (int r = 0; r < 4; ++r) {
        int row = mf * 16 + qr * 4 + r;
        *(unsigned short*)(smem + row * 776 + soff) = f2bf(fin(acc[mf][n][r]));
      }
  }
  __syncthreads();
#pragma unroll
  for (int j = 0; j < 8; ++j) {
    int row = wave * 8 + j;
    int rg  = m0 + row;
    if (rg < N_NODES) {
      u3 val = *(const u3*)(smem + row * 776 + lane * 12);
      *(u3*)((char*)C + (size_t)rg * 768 + lane * 12) = val;
    }
  }
}

// ---------------- edge aggregation: depth-4 pipeline, wave per node ------------
// Round-7 optimum restored VERBATIM (66.5us, VGPR 36, occupancy 62-72%).
// Round-8 (depth-8: VGPR 64, occ 38%) and round-9 (4-node blocks: occ 40%,
// degree-imbalance holds block slots) both regressed — wave-level latency
// hiding with 1-wave workgroups is the measured sweet spot.
#define EBODY(q) do { \
    uint _qa[3] = {(q).x, (q).y, (q).z}; \
    _Pragma("unroll") \
    for (int k = 0; k < 3; ++k) { \
      floatx2 sv; \
      sv.x = __uint_as_float(_qa[k] << 16); \
      sv.y = __uint_as_float(_qa[k] & 0xffff0000u); \
      floatx2 t = sv + r2[k]; \
      t = __builtin_elementwise_max(t, t * 0.2f); \
      floatx2 dw = t * a2[k]; \
      float w = dw.x + dw.y; \
      REDUCE16(w); \
      w = fminf(fmaxf(w, -126.f), 126.f); \
      float p = EXP2F(w); \
      l[k] += p; \
      floatx2 pv = {p, p}; \
      acc[k] += pv * sv; \
    } } while (0)

__global__ void k_edge(const unsigned short* __restrict__ XL, const unsigned short* __restrict__ XR,
                       const int* __restrict__ row_start, const int* __restrict__ csr_off,
                       const float* __restrict__ attp, const float* __restrict__ biasp,
                       unsigned short* __restrict__ H) {
  int v = blockIdx.x;
  int L = threadIdx.x;
  int Lo = L * 12;
  floatx2 r2[3], a2[3];
  u3 rv3 = *(const u3*)((const char*)XR + (size_t)v * 768 + Lo);
  uint rr[3] = {rv3.x, rv3.y, rv3.z};
  const floatx2* ap = (const floatx2*)(attp + L * 6);
#pragma unroll
  for (int k = 0; k < 3; ++k) {
    r2[k].x = __uint_as_float(rr[k] << 16);
    r2[k].y = __uint_as_float(rr[k] & 0xffff0000u);
    a2[k] = ap[k];
  }
  float l[3] = {0.f, 0.f, 0.f};
  floatx2 acc[3];
#pragma unroll
  for (int k = 0; k < 3; ++k) acc[k] = (floatx2){0.f, 0.f};
  int beg = row_start[v], end = row_start[v + 1];
  if (beg < 0) beg = 0;
  if (end > EN_TOT) end = EN_TOT;
  const char* XLb = (const char*)XL;
  const unsigned OMAX = (N_NODES - 1) * 768u;
  for (int base = beg; base < end; base += 64) {
    int nE = end - base; if (nE > 64) nE = 64;
    int last = nE - 1;
    int offv = (base + L < end) ? csr_off[base + L] : 0;   // coalesced chunk load
#define RLD(i) ({ int _i = (i) > last ? last : (i); \
                  int _s = __builtin_amdgcn_readlane(offv, _i); \
                  if ((unsigned)_s > OMAX) _s = 0; \
                  *(const u3*)(XLb + (unsigned)_s + Lo); })
    u3 q0 = RLD(0), q1 = RLD(1), q2 = RLD(2), q3 = RLD(3);
    int j = 0;
    for (; j + 4 <= nE; j += 4) {
      u3 n0 = RLD(j + 4), n1 = RLD(j + 5), n2 = RLD(j + 6), n3 = RLD(j + 7);
      EBODY(q0); EBODY(q1); EBODY(q2); EBODY(q3);
      q0 = n0; q1 = n1; q2 = n2; q3 = n3;
    }
    if (j < nE)     EBODY(q0);
    if (j + 1 < nE) EBODY(q1);
    if (j + 2 < nE) EBODY(q2);
#undef RLD
  }
  const floatx2* bp = (const floatx2*)(biasp + L * 6);
  uint* hr = (uint*)(H + (size_t)v * HC);
#pragma unroll
  for (int k = 0; k < 3; ++k) {
    floatx2 bb = bp[k];
    float inv = 1.f / fmaxf(l[k], 1e-30f);
    float o0 = acc[k].x * inv + bb.x;
    float o1 = acc[k].y * inv + bb.y;
    o0 = o0 > 0.f ? o0 : EXP2F(o0 * LOG2E) - 1.f;   // ELU via exp2
    o1 = o1 > 0.f ? o1 : EXP2F(o1 * LOG2E) - 1.f;
    hr[L + 64 * k] = (uint)f2bf(fin(o0)) | ((uint)f2bf(fin(o1)) << 16);
  }
}

// ---------------- fused MLP head: ELU(H2@W3+b3)@W4+b4 -> log_softmax -----------
__global__ void k_mlp(const unsigned short* __restrict__ H2,
                      const unsigned short* __restrict__ Bp3,
                      const unsigned short* __restrict__ Bp4,
                      const float* __restrict__ b3p, const float* __restrict__ b4p,
                      float* __restrict__ out) {
  __shared__ float hs[16][33];
  int lane = threadIdx.x;
  int m0   = blockIdx.x * 16;
  int row  = m0 + (lane & 15);
  int kk   = (lane >> 4) * 8;
  floatx4 acc[2];
  acc[0] = (floatx4){0.f, 0.f, 0.f, 0.f};
  acc[1] = (floatx4){0.f, 0.f, 0.f, 0.f};
#pragma unroll
  for (int kt = 0; kt < 12; ++kt) {
    short8 af = *(const short8*)(H2 + (size_t)row * HC + kt * 32 + kk);
    const short8* bp = (const short8*)Bp3 + (size_t)kt * 2 * 64 + lane;
    acc[0] = __builtin_amdgcn_mfma_f32_16x16x32_bf16(af, bp[0],  acc[0], 0, 0, 0);
    acc[1] = __builtin_amdgcn_mfma_f32_16x16x32_bf16(af, bp[64], acc[1], 0, 0, 0);
  }
  int qr = lane >> 4, cc = lane & 15;
#pragma unroll
  for (int nt = 0; nt < 2; ++nt)
#pragma unroll
    for (int r = 0; r < 4; ++r) {
      int col = nt * 16 + cc;
      float s = acc[nt][r] + b3p[col];
      s = s > 0.f ? s : EXP2F(s * LOG2E) - 1.f;
      hs[qr * 4 + r][col] = fin(s);
    }
  __syncthreads();
  short8 a2f;
#pragma unroll
  for (int j = 0; j < 8; ++j) a2f[j] = (short)f2bf(hs[lane & 15][kk + j]);
  floatx4 lg[3];
#pragma unroll
  for (int nt = 0; nt < 3; ++nt) {
    floatx4 z = (floatx4){0.f, 0.f, 0.f, 0.f};
    lg[nt] = __builtin_amdgcn_mfma_f32_16x16x32_bf16(a2f, ((const short8*)Bp4)[nt * 64 + lane], z, 0, 0, 0);
  }
  float bv[3];
#pragma unroll
  for (int nt = 0; nt < 3; ++nt) {
    int c = nt * 16 + cc;
    bv[nt] = (c < CLASSES) ? b4p[c] : 0.f;
  }
#pragma unroll
  for (int r = 0; r < 4; ++r) {
    float v0 = lg[0][r] + bv[0];
    float v1 = lg[1][r] + bv[1];
    float v2 = (cc < 8) ? (lg[2][r] + bv[2]) : -1e30f;
    float mx = fmaxf(fmaxf(v0, v1), v2);
    RED16MAX(mx);
    float sm = __expf(v0 - mx) + __expf(v1 - mx) + ((cc < 8) ? __expf(v2 - mx) : 0.f);
    sm = (sm == sm) ? sm : 1.f;
    REDUCE16(sm);
    float ls = mx + logf(sm);
    float* op = out + (size_t)(m0 + qr * 4 + r) * CLASSES;
    op[cc]      = fin(v0 - ls);
    op[16 + cc] = fin(v1 - ls);
    if (cc < 8) op[32 + cc] = fin(v2 - ls);
  }
}

extern "C" void kernel_launch(void* const* d_in, const int* in_sizes, int n_in,
                              void* d_out, int out_size, void* d_ws, size_t ws_size,
                              hipStream_t stream) {
  const void* x   = d_in[0];
  const int* ei   = (const int*)d_in[1];
  const void* Wl1 = d_in[2];
  const void* Wr1 = d_in[3];
  const void* a1  = d_in[4];
  const void* b1  = d_in[5];
  const void* Wl2 = d_in[6];
  const void* Wr2 = d_in[7];
  const void* a2  = d_in[8];
  const void* b2  = d_in[9];
  const void* W3  = d_in[10];
  const void* b3  = d_in[11];
  const void* W4  = d_in[12];
  const void* b4  = d_in[13];
  float* out = (float*)d_out;

  char* ws = (char*)d_ws;
  size_t off = 0;
  auto alloc = [&](size_t bytes) { size_t o = off; off += (bytes + 255) & ~(size_t)255; return o; };
  int* flag       = (int*)(ws + alloc(256));
  int* row_start  = (int*)(ws + alloc((size_t)(N_NODES + 1) * 4));
  int* counts     = (int*)(ws + alloc((size_t)N_NODES * 4));
  int* cursor     = (int*)(ws + alloc((size_t)N_NODES * 4));
  int* bsum       = (int*)(ws + alloc(64 * 4));
  int* csr_off    = (int*)(ws + alloc((size_t)EN_TOT * 4));
  unsigned short* BpL1 = (unsigned short*)(ws + alloc((size_t)F_IN * HC * 2));
  unsigned short* BpR1 = (unsigned short*)(ws + alloc((size_t)F_IN * HC * 2));
  unsigned short* BpL2 = (unsigned short*)(ws + alloc((size_t)HC * HC * 2));
  unsigned short* BpR2 = (unsigned short*)(ws + alloc((size_t)HC * HC * 2));
  unsigned short* Bp3  = (unsigned short*)(ws + alloc((size_t)HC * 32 * 2));
  unsigned short* Bp4  = (unsigned short*)(ws + alloc((size_t)32 * 48 * 2));
  float* attp1  = (float*)(ws + alloc(768 * 4));
  float* attp2  = (float*)(ws + alloc(768 * 4));
  float* biasp1 = (float*)(ws + alloc(768 * 4));
  float* biasp2 = (float*)(ws + alloc(768 * 4));
  float* b3p    = (float*)(ws + alloc(32 * 4));
  float* b4p    = (float*)(ws + alloc(40 * 4));
  unsigned short* B0   = (unsigned short*)(ws + alloc((size_t)N_NODES * HC * 2));
  unsigned short* B1   = (unsigned short*)(ws + alloc((size_t)N_NODES * HC * 2));
  unsigned short* B2   = (unsigned short*)(ws + alloc((size_t)N_NODES * HC * 2));
  (void)in_sizes; (void)n_in;

  if (ws_size < off) {
    k_sentinel<<<(out_size + 255) / 256, 256, 0, stream>>>(out, out_size);
    return;
  }

  const int SCAN_BLOCKS = (N_NODES + 1023) / 1024;   // 49
  const int GEMM_BLOCKS = 2 * ((N_NODES + 31) / 32); // 3126 (dual, 32-row tiles)

  // --- CSR by dst (+ dtype detect fused into the zeroing pass) ---
  k_detect_zero<<<(N_NODES + 255) / 256, 256, 0, stream>>>((const unsigned short*)x, flag, counts, cursor);
  k_count<<<(EN_TOT + 255) / 256, 256, 0, stream>>>(ei, counts);
  k_scan1<<<SCAN_BLOCKS, 1024, 0, stream>>>(counts, row_start, bsum);
  k_scan23<<<SCAN_BLOCKS, 1024, 0, stream>>>(row_start, bsum, SCAN_BLOCKS);
  k_fill<<<(EN_TOT + 255) / 256, 256, 0, stream>>>(ei, row_start, cursor, csr_off);

  // --- pack all weights + f32 att/bias prepack in one launch ---
  k_pack_all<<<(PK_TOT + 255) / 256, 256, 0, stream>>>(Wl1, Wr1, Wl2, Wr2, W3, W4,
                                                       a1, a2, b1, b2, b3, b4,
                                                       BpL1, BpR1, BpL2, BpR2, Bp3, Bp4,
                                                       attp1, attp2, biasp1, biasp2, b3p, b4p, flag);

  // --- layer 1 (K=128): dual-output GEMM straight from x (fp32 cvt in staging) ---
  k_gemm2<4, 1><<<GEMM_BLOCKS, 256, 0, stream>>>(x, BpL1, BpR1, B0, B1, flag);
  k_edge<<<N_NODES, 64, 0, stream>>>(B0, B1, row_start, csr_off, attp1, biasp1, B1);

  // --- layer 2 (K=384): dual-output GEMM ---
  k_gemm2<12, 0><<<GEMM_BLOCKS, 256, 0, stream>>>(B1, BpL2, BpR2, B2, B0, flag);
  k_edge<<<N_NODES, 64, 0, stream>>>(B2, B0, row_start, csr_off, attp2, biasp2, B1);

  // --- fused MLP head + log_softmax ---
  k_mlp<<<N_NODES / 16, 64, 0, stream>>>(B1, Bp3, Bp4, b3p, b4p, out);
}

// Round 11
// 348.071 us; speedup vs baseline: 1.0409x; 1.0409x over previous
//
#include <hip/hip_runtime.h>
#include <hip/hip_bf16.h>
#include <math.h>

#define N_NODES 50000
#define E_EDGES 400000
#define EN_TOT  (E_EDGES + N_NODES)
#define F_IN    128
#define HC      384
#define CLASSES 40
#define LOG2E   1.44269504088896f

typedef short short8 __attribute__((ext_vector_type(8)));
typedef float floatx4 __attribute__((ext_vector_type(4)));
typedef float floatx2 __attribute__((ext_vector_type(2)));
typedef unsigned int uint;

struct u3 { uint x, y, z; };   // 12B, align 4

__device__ __forceinline__ float bf2f(unsigned short u) {
  union { unsigned int i; float f; } x; x.i = ((unsigned int)u) << 16; return x.f;
}
__device__ __forceinline__ unsigned short f2bf(float f) {
  union { float f; unsigned int i; } x; x.f = f;
  unsigned int r = x.i + 0x7fffu + ((x.i >> 16) & 1u);
  return (unsigned short)(r >> 16);
}
__device__ __forceinline__ float fin(float v) {        // NaN/Inf -> 0 (no-op on healthy path)
  return (fabsf(v) < 1e30f) ? v : 0.f;
}
__device__ __forceinline__ float rdw(const void* p, int idx, int fp32) {
  return fp32 ? ((const float*)p)[idx] : bf2f(((const unsigned short*)p)[idx]);
}

#if __has_builtin(__builtin_amdgcn_exp2f)
#define EXP2F(x) __builtin_amdgcn_exp2f(x)
#else
#define EXP2F(x) exp2f(x)
#endif

// 16-lane reduce broadcast via v_add/max_f32_dpp butterfly (row=16 aligned groups).
#if __has_builtin(__builtin_amdgcn_update_dpp)
#define DPP_ADD(w, ctrl) \
  (w += __int_as_float(__builtin_amdgcn_update_dpp(0, __float_as_int(w), ctrl, 0xf, 0xf, true)))
#define REDUCE16(w) do { DPP_ADD(w, 0xB1); DPP_ADD(w, 0x4E); DPP_ADD(w, 0x141); DPP_ADD(w, 0x140); } while (0)
#define DPP_MAXF(w, ctrl) do { float _t = __int_as_float(__builtin_amdgcn_update_dpp(0, \
    __float_as_int(w), ctrl, 0xf, 0xf, true)); w = fmaxf(w, _t); } while (0)
#define RED16MAX(w) do { DPP_MAXF(w, 0xB1); DPP_MAXF(w, 0x4E); DPP_MAXF(w, 0x141); DPP_MAXF(w, 0x140); } while (0)
#else
#define REDUCE16(w) do { w += __shfl_xor(w, 1); w += __shfl_xor(w, 2); \
                         w += __shfl_xor(w, 4); w += __shfl_xor(w, 8); } while (0)
#define RED16MAX(w) do { w = fmaxf(w, __shfl_xor(w, 1)); w = fmaxf(w, __shfl_xor(w, 2)); \
                         w = fmaxf(w, __shfl_xor(w, 4)); w = fmaxf(w, __shfl_xor(w, 8)); } while (0)
#endif

// swizzled row layout for GEMM outputs feeding k_edge:
// channel c (0..383): k = c>>7, L = (c&127)>>1, b = c&1 -> byte off = L*12 + k*4 + b*2.
// Lane L of k_edge reads its 3 channel-pair dwords as ONE dwordx3 at row*768 + L*12.

__global__ void k_sentinel(float* out, int n) {
  int i = blockIdx.x * 256 + threadIdx.x;
  if (i < n) out[i] = 111.0f;
}

// ---------------- fused: zero counts/cursor + dtype detect (block 0, wave 0) ----
__global__ void k_detect_zero(const unsigned short* __restrict__ x, int* __restrict__ flag,
                              int* __restrict__ counts, int* __restrict__ cursor) {
  int i = blockIdx.x * 256 + threadIdx.x;
  if (i < N_NODES) { counts[i] = 0; cursor[i] = 0; }
  if (blockIdx.x == 0 && threadIdx.x < 64) {
    int L = threadIdx.x;
    int sane = 0;
#pragma unroll
    for (int t = 0; t < 4; ++t) {
      unsigned short u = x[(size_t)(L * 4 + t) * 2];
      unsigned int mag = u & 0x7FFFu;
      unsigned int e   = (u >> 7) & 0xFFu;
      if (mag == 0u || (e >= 96u && e <= 159u)) sane++;
    }
    sane += __shfl_xor(sane, 1);
    sane += __shfl_xor(sane, 2);
    sane += __shfl_xor(sane, 4);
    sane += __shfl_xor(sane, 8);
    sane += __shfl_xor(sane, 16);
    sane += __shfl_xor(sane, 32);
    if (L == 0) flag[0] = (sane < 179) ? 1 : 0;   // 1 => inputs are fp32
  }
}

__global__ void k_count(const int* __restrict__ ei, int* __restrict__ counts) {
  int e = blockIdx.x * 256 + threadIdx.x;
  if (e >= EN_TOT) return;
  int dst = (e < E_EDGES) ? ei[E_EDGES + e] : (e - E_EDGES);
  if ((unsigned)dst < N_NODES) atomicAdd(&counts[dst], 1);
}

__global__ void k_scan1(const int* __restrict__ counts, int* __restrict__ row_start,
                        int* __restrict__ bsum) {
  int b = blockIdx.x, tid = threadIdx.x;
  int i = b * 1024 + tid;
  int v = (i < N_NODES) ? counts[i] : 0;
  int lane = tid & 63, w = tid >> 6;
  int x = v;
#pragma unroll
  for (int d = 1; d < 64; d <<= 1) { int t = __shfl_up(x, d); if (lane >= d) x += t; }
  __shared__ int wsum[16];
  if (lane == 63) wsum[w] = x;
  __syncthreads();
  if (w == 0) {
    int y = (lane < 16) ? wsum[lane] : 0;
#pragma unroll
    for (int d = 1; d < 16; d <<= 1) { int t = __shfl_up(y, d); if (lane >= d) y += t; }
    if (lane < 16) wsum[lane] = y;
  }
  __syncthreads();
  if (w > 0) x += wsum[w - 1];
  if (i < N_NODES) row_start[i + 1] = x;
  if (tid == 1023) bsum[b] = x;
}

// fused scan2+scan3: every block redundantly scans the 49 block sums (cheap).
__global__ void k_scan23(int* __restrict__ row_start, const int* __restrict__ bsum, int nb) {
  int b = blockIdx.x, tid = threadIdx.x;
  __shared__ int sadd;
  if (tid < 64) {
    int lane = tid;
    int x = (lane < nb) ? bsum[lane] : 0;
#pragma unroll
    for (int d = 1; d < 64; d <<= 1) { int t = __shfl_up(x, d); if (lane >= d) x += t; }
    int pre = __shfl(x, (b > 0) ? (b - 1) : 0);
    if (tid == 0) sadd = (b > 0) ? pre : 0;
  }
  __syncthreads();
  int add = sadd;
  int i = b * 1024 + tid;
  if (i < N_NODES) row_start[i + 1] += add;
  if (i == 0) row_start[0] = 0;
}

// stores PRE-MULTIPLIED byte offsets (src*768).
__global__ void k_fill(const int* __restrict__ ei, const int* __restrict__ row_start,
                       int* __restrict__ cursor, int* __restrict__ csr_off) {
  int e = blockIdx.x * 256 + threadIdx.x;
  if (e >= EN_TOT) return;
  int src, dst;
  if (e < E_EDGES) { src = ei[e]; dst = ei[E_EDGES + e]; }
  else             { src = dst = e - E_EDGES; }
  if ((unsigned)dst >= N_NODES) return;
  int sv = ((unsigned)src < N_NODES) ? src : 0;
  int pos = atomicAdd(&cursor[dst], 1);
  int slot = row_start[dst] + pos;
  if ((unsigned)slot < EN_TOT) csr_off[slot] = sv * 768;
}

// ---------------- pack weights into MFMA frag order + att/bias f32 prepack ------
#define PK_J1 (F_IN * HC)          // 49152
#define PK_J2 (2 * PK_J1)          // 98304
#define PK_J3 (PK_J2 + HC * HC)    // 245760
#define PK_J4 (PK_J3 + HC * HC)    // 393216
#define PK_J5 (PK_J4 + HC * 32)    // 405504
#define PK_J6 (PK_J5 + 32 * 48)    // 407040 (W4 [32x40] zero-padded to 48 cols)
#define PK_EX 3144                 // att1,att2,bias1,bias2 (768 ea) + b3(32) + b4(40)
#define PK_TOT (PK_J6 + PK_EX)
// att/bias lane-major layout: idx i = L*6 + 2k + b  <->  channel c = 2L + 128k + b.
__global__ void k_pack_all(const void* __restrict__ Wl1, const void* __restrict__ Wr1,
                           const void* __restrict__ Wl2, const void* __restrict__ Wr2,
                           const void* __restrict__ W3, const void* __restrict__ W4,
                           const void* __restrict__ a1_, const void* __restrict__ a2_,
                           const void* __restrict__ b1_, const void* __restrict__ b2_,
                           const void* __restrict__ b3_, const void* __restrict__ b4_,
                           unsigned short* __restrict__ BpL1, unsigned short* __restrict__ BpR1,
                           unsigned short* __restrict__ BpL2, unsigned short* __restrict__ BpR2,
                           unsigned short* __restrict__ Bp3, unsigned short* __restrict__ Bp4,
                           float* __restrict__ attp1, float* __restrict__ attp2,
                           float* __restrict__ biasp1, float* __restrict__ biasp2,
                           float* __restrict__ b3p, float* __restrict__ b4p,
                           const int* __restrict__ flagp) {
  int gid = blockIdx.x * 256 + threadIdx.x;
  if (gid >= PK_TOT) return;
  int fp32 = flagp[0];
  if (gid >= PK_J6) {                       // f32 extras
    int i = gid - PK_J6;
    if (i < 3072) {
      int seg = i / 768, r = i % 768;
      int L = r / 6, q = r % 6, k = q >> 1, b = q & 1;
      int c = 2 * L + 128 * k + b;
      if (seg == 0)      attp1[r]  = fin(rdw(a1_, c, fp32)) * LOG2E;
      else if (seg == 1) attp2[r]  = fin(rdw(a2_, c, fp32)) * LOG2E;
      else if (seg == 2) biasp1[r] = fin(rdw(b1_, c, fp32));
      else               biasp2[r] = fin(rdw(b2_, c, fp32));
    } else if (i < 3104) b3p[i - 3072] = fin(rdw(b3_, i - 3072, fp32));
    else                 b4p[i - 3104] = fin(rdw(b4_, i - 3104, fp32));
    return;
  }
  const void* src; unsigned short* dst; int NT, NCOL, idx;
  if (gid < PK_J2)      { NT = 24; NCOL = 384; if (gid < PK_J1) { src = Wl1; dst = BpL1; idx = gid; }
                                               else             { src = Wr1; dst = BpR1; idx = gid - PK_J1; } }
  else if (gid < PK_J4) { NT = 24; NCOL = 384; if (gid < PK_J3) { src = Wl2; dst = BpL2; idx = gid - PK_J2; }
                                               else             { src = Wr2; dst = BpR2; idx = gid - PK_J3; } }
  else if (gid < PK_J5) { NT = 2;  NCOL = 32;  src = W3; dst = Bp3; idx = gid - PK_J4; }
  else                  { NT = 3;  NCOL = 40;  src = W4; dst = Bp4; idx = gid - PK_J5; }
  int j  = idx & 7;
  int L  = (idx >> 3) & 63;
  int t  = idx >> 9;       // kt*NT + nt
  int nt = t % NT;
  int kt = t / NT;
  int k  = kt * 32 + ((L >> 4) * 8) + j;
  int n  = nt * 16 + (L & 15);
  float v = (n < NCOL) ? rdw(src, k * NCOL + n, fp32) : 0.f;
  dst[idx] = f2bf(fin(v));
}

// ---------------- dual GEMM: 32-row tile, 3-buffer B prefetch (PROVEN R9) -------
// Round-10 lesson: 2-buffer depth-1 prefetch re-serialized the B stream
// (-8us total); the 3-buffer depth-2 rotation is the measured optimum.
// AF=1: A may be fp32 -> convert in the ONCE-PER-BLOCK staging loop.
#define LOADB(dst, kt) do { _Pragma("unroll") for (int n = 0; n < 6; ++n) \
    dst[n] = ((const short8*)Bp)[((size_t)((kt) * 24 + nt0 + n)) * 64 + lane]; } while (0)
#define DOMFMA(bf, kt) do { \
    short8 af[2]; \
    _Pragma("unroll") for (int mf = 0; mf < 2; ++mf) { \
      int row = mf * 16 + rsel; \
      int col = (kt) * 64 + kk16 * 16; \
      af[mf] = *(const short8*)(smem + row * RS + (col ^ ((row & 7) << 4))); } \
    _Pragma("unroll") for (int n = 0; n < 6; ++n) \
      _Pragma("unroll") for (int mf = 0; mf < 2; ++mf) \
        acc[mf][n] = __builtin_amdgcn_mfma_f32_16x16x32_bf16(af[mf], bf[n], acc[mf][n], 0, 0, 0); } while (0)

template<int NK, int AF>
__global__ __launch_bounds__(256, 4) void k_gemm2(const void* __restrict__ A_,
                       const unsigned short* __restrict__ BpL,
                       const unsigned short* __restrict__ BpR,
                       unsigned short* __restrict__ CL, unsigned short* __restrict__ CR,
                       const int* __restrict__ flagp) {
  constexpr int RS  = NK * 64;         // A row stride (bf16 bytes)
  constexpr int NST = NK / 2;          // staging iters (32 rows x RS / 4096B)
  __shared__ __align__(16) char smem[32 * 776];   // 24832B >= 32*RS (NK<=12)
  int which = blockIdx.x & 1;
  int bt    = blockIdx.x >> 1;
  const unsigned short* Bp = which ? BpR : BpL;
  unsigned short* C        = which ? CR  : CL;
  int fp32 = AF ? flagp[0] : 0;
  int tid  = threadIdx.x;
  int wave = tid >> 6, lane = tid & 63;
  int m0   = bt * 32;

  // ---- stage A tile (reg-staged, once; fp32 converted here; tail clamped) ----
  {
    uint4 v[NST];
#pragma unroll
    for (int i = 0; i < NST; ++i) {
      int o   = (i * 256 + tid) * 16;
      int row = o / RS;
      int rem = o - row * RS;
      int rg  = m0 + row; if (rg >= N_NODES) rg = N_NODES - 1;
      if (AF && fp32) {
        const float* p = (const float*)((const char*)A_ + ((size_t)rg * RS + rem) * 2);
        floatx4 f0 = *(const floatx4*)p;
        floatx4 f1 = *(const floatx4*)(p + 4);
        short8 o8;
#pragma unroll
        for (int j = 0; j < 4; ++j) { o8[j] = (short)f2bf(f0[j]); o8[4 + j] = (short)f2bf(f1[j]); }
        v[i] = *(uint4*)&o8;
      } else {
        v[i] = *(const uint4*)((const char*)A_ + (size_t)rg * RS + rem);
      }
    }
#pragma unroll
    for (int i = 0; i < NST; ++i) {
      int o   = (i * 256 + tid) * 16;
      int row = o / RS;
      int rem = o - row * RS;
      *(uint4*)(smem + row * RS + (rem ^ ((row & 7) << 4))) = v[i];
    }
  }

  int nt0  = wave * 6;
  int kk16 = (lane >> 4);
  int rsel = lane & 15;
  floatx4 acc[2][6];
#pragma unroll
  for (int mf = 0; mf < 2; ++mf)
#pragma unroll
    for (int n = 0; n < 6; ++n) acc[mf][n] = (floatx4){0.f, 0.f, 0.f, 0.f};

  short8 b0[6], b1[6], b2[6];
  LOADB(b0, 0);
  LOADB(b1, 1);
  __syncthreads();               // A tile ready

#pragma unroll
  for (int kt = 0; kt < NK; ++kt) {
    if (kt + 2 < NK) {
      if (((kt + 2) % 3) == 0)      LOADB(b0, kt + 2);
      else if (((kt + 2) % 3) == 1) LOADB(b1, kt + 2);
      else                          LOADB(b2, kt + 2);
    }
    if ((kt % 3) == 0)      DOMFMA(b0, kt);
    else if ((kt % 3) == 1) DOMFMA(b1, kt);
    else                    DOMFMA(b2, kt);
  }

  // ---- epilogue: LDS re-staged wide stores (swizzled row layout) ----
  __syncthreads();
  int qr = lane >> 4, ccol = lane & 15;
#pragma unroll
  for (int n = 0; n < 6; ++n) {
    int c    = (nt0 + n) * 16 + ccol;
    int soff = ((c & 127) >> 1) * 12 + (c >> 7) * 4 + (c & 1) * 2;
#pragma unroll
    for (int mf = 0; mf < 2; ++mf)
#pragma unroll
      for (int r = 0; r < 4; ++r) {
        int row = mf * 16 + qr * 4 + r;
        *(unsigned short*)(smem + row * 776 + soff) = f2bf(fin(acc[mf][n][r]));
      }
  }
  __syncthreads();
#pragma unroll
  for (int j = 0; j < 8; ++j) {
    int row = wave * 8 + j;
    int rg  = m0 + row;
    if (rg < N_NODES) {
      u3 val = *(const u3*)(smem + row * 776 + lane * 12);
      *(u3*)((char*)C + (size_t)rg * 768 + lane * 12) = val;
    }
  }
}

// ---------------- edge aggregation: depth-4 pipeline, wave per node ------------
// Round-7 optimum (66.5us, VGPR 36, occupancy 62-72%). Depth-8 (R8) and
// 4-node blocks (R9) both regressed; this is the measured sweet spot.
#define EBODY(q) do { \
    uint _qa[3] = {(q).x, (q).y, (q).z}; \
    _Pragma("unroll") \
    for (int k = 0; k < 3; ++k) { \
      floatx2 sv; \
      sv.x = __uint_as_float(_qa[k] << 16); \
      sv.y = __uint_as_float(_qa[k] & 0xffff0000u); \
      floatx2 t = sv + r2[k]; \
      t = __builtin_elementwise_max(t, t * 0.2f); \
      floatx2 dw = t * a2[k]; \
      float w = dw.x + dw.y; \
      REDUCE16(w); \
      w = fminf(fmaxf(w, -126.f), 126.f); \
      float p = EXP2F(w); \
      l[k] += p; \
      floatx2 pv = {p, p}; \
      acc[k] += pv * sv; \
    } } while (0)

__global__ void k_edge(const unsigned short* __restrict__ XL, const unsigned short* __restrict__ XR,
                       const int* __restrict__ row_start, const int* __restrict__ csr_off,
                       const float* __restrict__ attp, const float* __restrict__ biasp,
                       unsigned short* __restrict__ H) {
  int v = blockIdx.x;
  int L = threadIdx.x;
  int Lo = L * 12;
  floatx2 r2[3], a2[3];
  u3 rv3 = *(const u3*)((const char*)XR + (size_t)v * 768 + Lo);
  uint rr[3] = {rv3.x, rv3.y, rv3.z};
  const floatx2* ap = (const floatx2*)(attp + L * 6);
#pragma unroll
  for (int k = 0; k < 3; ++k) {
    r2[k].x = __uint_as_float(rr[k] << 16);
    r2[k].y = __uint_as_float(rr[k] & 0xffff0000u);
    a2[k] = ap[k];
  }
  float l[3] = {0.f, 0.f, 0.f};
  floatx2 acc[3];
#pragma unroll
  for (int k = 0; k < 3; ++k) acc[k] = (floatx2){0.f, 0.f};
  int beg = row_start[v], end = row_start[v + 1];
  if (beg < 0) beg = 0;
  if (end > EN_TOT) end = EN_TOT;
  const char* XLb = (const char*)XL;
  const unsigned OMAX = (N_NODES - 1) * 768u;
  for (int base = beg; base < end; base += 64) {
    int nE = end - base; if (nE > 64) nE = 64;
    int last = nE - 1;
    int offv = (base + L < end) ? csr_off[base + L] : 0;   // coalesced chunk load
#define RLD(i) ({ int _i = (i) > last ? last : (i); \
                  int _s = __builtin_amdgcn_readlane(offv, _i); \
                  if ((unsigned)_s > OMAX) _s = 0; \
                  *(const u3*)(XLb + (unsigned)_s + Lo); })
    u3 q0 = RLD(0), q1 = RLD(1), q2 = RLD(2), q3 = RLD(3);
    int j = 0;
    for (; j + 4 <= nE; j += 4) {
      u3 n0 = RLD(j + 4), n1 = RLD(j + 5), n2 = RLD(j + 6), n3 = RLD(j + 7);
      EBODY(q0); EBODY(q1); EBODY(q2); EBODY(q3);
      q0 = n0; q1 = n1; q2 = n2; q3 = n3;
    }
    if (j < nE)     EBODY(q0);
    if (j + 1 < nE) EBODY(q1);
    if (j + 2 < nE) EBODY(q2);
#undef RLD
  }
  const floatx2* bp = (const floatx2*)(biasp + L * 6);
  uint* hr = (uint*)(H + (size_t)v * HC);
#pragma unroll
  for (int k = 0; k < 3; ++k) {
    floatx2 bb = bp[k];
    float inv = 1.f / fmaxf(l[k], 1e-30f);
    float o0 = acc[k].x * inv + bb.x;
    float o1 = acc[k].y * inv + bb.y;
    o0 = o0 > 0.f ? o0 : EXP2F(o0 * LOG2E) - 1.f;   // ELU via exp2
    o1 = o1 > 0.f ? o1 : EXP2F(o1 * LOG2E) - 1.f;
    hr[L + 64 * k] = (uint)f2bf(fin(o0)) | ((uint)f2bf(fin(o1)) << 16);
  }
}

// ---------------- fused MLP head: ELU(H2@W3+b3)@W4+b4 -> log_softmax -----------
__global__ void k_mlp(const unsigned short* __restrict__ H2,
                      const unsigned short* __restrict__ Bp3,
                      const unsigned short* __restrict__ Bp4,
                      const float* __restrict__ b3p, const float* __restrict__ b4p,
                      float* __restrict__ out) {
  __shared__ float hs[16][33];
  int lane = threadIdx.x;
  int m0   = blockIdx.x * 16;
  int row  = m0 + (lane & 15);
  int kk   = (lane >> 4) * 8;
  floatx4 acc[2];
  acc[0] = (floatx4){0.f, 0.f, 0.f, 0.f};
  acc[1] = (floatx4){0.f, 0.f, 0.f, 0.f};
#pragma unroll
  for (int kt = 0; kt < 12; ++kt) {
    short8 af = *(const short8*)(H2 + (size_t)row * HC + kt * 32 + kk);
    const short8* bp = (const short8*)Bp3 + (size_t)kt * 2 * 64 + lane;
    acc[0] = __builtin_amdgcn_mfma_f32_16x16x32_bf16(af, bp[0],  acc[0], 0, 0, 0);
    acc[1] = __builtin_amdgcn_mfma_f32_16x16x32_bf16(af, bp[64], acc[1], 0, 0, 0);
  }
  int qr = lane >> 4, cc = lane & 15;
#pragma unroll
  for (int nt = 0; nt < 2; ++nt)
#pragma unroll
    for (int r = 0; r < 4; ++r) {
      int col = nt * 16 + cc;
      float s = acc[nt][r] + b3p[col];
      s = s > 0.f ? s : EXP2F(s * LOG2E) - 1.f;
      hs[qr * 4 + r][col] = fin(s);
    }
  __syncthreads();
  short8 a2f;
#pragma unroll
  for (int j = 0; j < 8; ++j) a2f[j] = (short)f2bf(hs[lane & 15][kk + j]);
  floatx4 lg[3];
#pragma unroll
  for (int nt = 0; nt < 3; ++nt) {
    floatx4 z = (floatx4){0.f, 0.f, 0.f, 0.f};
    lg[nt] = __builtin_amdgcn_mfma_f32_16x16x32_bf16(a2f, ((const short8*)Bp4)[nt * 64 + lane], z, 0, 0, 0);
  }
  float bv[3];
#pragma unroll
  for (int nt = 0; nt < 3; ++nt) {
    int c = nt * 16 + cc;
    bv[nt] = (c < CLASSES) ? b4p[c] : 0.f;
  }
#pragma unroll
  for (int r = 0; r < 4; ++r) {
    float v0 = lg[0][r] + bv[0];
    float v1 = lg[1][r] + bv[1];
    float v2 = (cc < 8) ? (lg[2][r] + bv[2]) : -1e30f;
    float mx = fmaxf(fmaxf(v0, v1), v2);
    RED16MAX(mx);
    float sm = __expf(v0 - mx) + __expf(v1 - mx) + ((cc < 8) ? __expf(v2 - mx) : 0.f);
    sm = (sm == sm) ? sm : 1.f;
    REDUCE16(sm);
    float ls = mx + logf(sm);
    float* op = out + (size_t)(m0 + qr * 4 + r) * CLASSES;
    op[cc]      = fin(v0 - ls);
    op[16 + cc] = fin(v1 - ls);
    if (cc < 8) op[32 + cc] = fin(v2 - ls);
  }
}

extern "C" void kernel_launch(void* const* d_in, const int* in_sizes, int n_in,
                              void* d_out, int out_size, void* d_ws, size_t ws_size,
                              hipStream_t stream) {
  const void* x   = d_in[0];
  const int* ei   = (const int*)d_in[1];
  const void* Wl1 = d_in[2];
  const void* Wr1 = d_in[3];
  const void* a1  = d_in[4];
  const void* b1  = d_in[5];
  const void* Wl2 = d_in[6];
  const void* Wr2 = d_in[7];
  const void* a2  = d_in[8];
  const void* b2  = d_in[9];
  const void* W3  = d_in[10];
  const void* b3  = d_in[11];
  const void* W4  = d_in[12];
  const void* b4  = d_in[13];
  float* out = (float*)d_out;

  char* ws = (char*)d_ws;
  size_t off = 0;
  auto alloc = [&](size_t bytes) { size_t o = off; off += (bytes + 255) & ~(size_t)255; return o; };
  int* flag       = (int*)(ws + alloc(256));
  int* row_start  = (int*)(ws + alloc((size_t)(N_NODES + 1) * 4));
  int* counts     = (int*)(ws + alloc((size_t)N_NODES * 4));
  int* cursor     = (int*)(ws + alloc((size_t)N_NODES * 4));
  int* bsum       = (int*)(ws + alloc(64 * 4));
  int* csr_off    = (int*)(ws + alloc((size_t)EN_TOT * 4));
  unsigned short* BpL1 = (unsigned short*)(ws + alloc((size_t)F_IN * HC * 2));
  unsigned short* BpR1 = (unsigned short*)(ws + alloc((size_t)F_IN * HC * 2));
  unsigned short* BpL2 = (unsigned short*)(ws + alloc((size_t)HC * HC * 2));
  unsigned short* BpR2 = (unsigned short*)(ws + alloc((size_t)HC * HC * 2));
  unsigned short* Bp3  = (unsigned short*)(ws + alloc((size_t)HC * 32 * 2));
  unsigned short* Bp4  = (unsigned short*)(ws + alloc((size_t)32 * 48 * 2));
  float* attp1  = (float*)(ws + alloc(768 * 4));
  float* attp2  = (float*)(ws + alloc(768 * 4));
  float* biasp1 = (float*)(ws + alloc(768 * 4));
  float* biasp2 = (float*)(ws + alloc(768 * 4));
  float* b3p    = (float*)(ws + alloc(32 * 4));
  float* b4p    = (float*)(ws + alloc(40 * 4));
  unsigned short* B0   = (unsigned short*)(ws + alloc((size_t)N_NODES * HC * 2));
  unsigned short* B1   = (unsigned short*)(ws + alloc((size_t)N_NODES * HC * 2));
  unsigned short* B2   = (unsigned short*)(ws + alloc((size_t)N_NODES * HC * 2));
  (void)in_sizes; (void)n_in;

  if (ws_size < off) {
    k_sentinel<<<(out_size + 255) / 256, 256, 0, stream>>>(out, out_size);
    return;
  }

  const int SCAN_BLOCKS = (N_NODES + 1023) / 1024;   // 49
  const int GEMM_BLOCKS = 2 * ((N_NODES + 31) / 32); // 3126 (dual, 32-row tiles)

  // --- CSR by dst (+ dtype detect fused into the zeroing pass) ---
  k_detect_zero<<<(N_NODES + 255) / 256, 256, 0, stream>>>((const unsigned short*)x, flag, counts, cursor);
  k_count<<<(EN_TOT + 255) / 256, 256, 0, stream>>>(ei, counts);
  k_scan1<<<SCAN_BLOCKS, 1024, 0, stream>>>(counts, row_start, bsum);
  k_scan23<<<SCAN_BLOCKS, 1024, 0, stream>>>(row_start, bsum, SCAN_BLOCKS);
  k_fill<<<(EN_TOT + 255) / 256, 256, 0, stream>>>(ei, row_start, cursor, csr_off);

  // --- pack all weights + f32 att/bias prepack in one launch ---
  k_pack_all<<<(PK_TOT + 255) / 256, 256, 0, stream>>>(Wl1, Wr1, Wl2, Wr2, W3, W4,
                                                       a1, a2, b1, b2, b3, b4,
                                                       BpL1, BpR1, BpL2, BpR2, Bp3, Bp4,
                                                       attp1, attp2, biasp1, biasp2, b3p, b4p, flag);

  // --- layer 1 (K=128): dual-output GEMM straight from x (fp32 cvt in staging) ---
  k_gemm2<4, 1><<<GEMM_BLOCKS, 256, 0, stream>>>(x, BpL1, BpR1, B0, B1, flag);
  k_edge<<<N_NODES, 64, 0, stream>>>(B0, B1, row_start, csr_off, attp1, biasp1, B1);

  // --- layer 2 (K=384): dual-output GEMM ---
  k_gemm2<12, 0><<<GEMM_BLOCKS, 256, 0, stream>>>(B1, BpL2, BpR2, B2, B0, flag);
  k_edge<<<N_NODES, 64, 0, stream>>>(B2, B0, row_start, csr_off, attp2, biasp2, B1);

  // --- fused MLP head + log_softmax ---
  k_mlp<<<N_NODES / 16, 64, 0, stream>>>(B1, Bp3, Bp4, b3p, b4p, out);
}